// Round 8
// baseline (43.676 us; speedup 1.0000x reference)
//
#include <hip/hip_runtime.h>

#define NB 32
#define CC 3
#define HH 512
#define WW 512
#define KS 25
#define PAD 12
#define HT 8                  // output rows per block (full 512-wide strip)
#define LDSW 536              // 12 halo + 512 + 12 halo floats per LDS row
#define BATCH 16              // vertical rows preloaded per register batch

__device__ __forceinline__ float clamp01(float v) {
    return fminf(fmaxf(v, 0.0f), 1.0f);
}

// EDGE=false: strips 2..61, no bounds checks anywhere (94% of blocks).
template<bool EDGE>
__device__ __forceinline__ void blur_body(const float* __restrict__ ibase,
                                          float* __restrict__ obase,
                                          int r0, int tid, float* tile) {
    constexpr float W[KS] = {
        0.02181520f, 0.02514307f, 0.02862302f, 0.03218484f, 0.03574584f,
        0.03921371f, 0.04249020f, 0.04547544f, 0.04807347f, 0.05019624f,
        0.05176967f, 0.05273727f, 0.05306384f, 0.05273727f, 0.05176967f,
        0.05019624f, 0.04807347f, 0.04547544f, 0.04249020f, 0.03921371f,
        0.03574584f, 0.03218484f, 0.02862302f, 0.02514307f, 0.02181520f};

    // zero left/right halos: 8 rows x 24 floats
    if (tid < HT * 2 * PAD) {
        int r = tid / (2 * PAD);
        int k = tid - r * (2 * PAD);
        tile[r * LDSW + (k < PAD ? k : 512 + k)] = 0.0f;
    }

    // ---- vertical: thread owns float2-column tid for ALL 8 rows ----
    // Two register batches of 16 rows each: issue 16 independent loads
    // back-to-back (deep MLP), then FMA the batch. VGPR=36 in round 7 meant
    // only ~5 loads in flight -> latency-exposed.
    const float* ip = ibase + tid * 2;
    float2 acc[HT];
#pragma unroll
    for (int j = 0; j < HT; ++j) acc[j] = make_float2(0.f, 0.f);

#pragma unroll
    for (int half = 0; half < 2; ++half) {
        float2 vv[BATCH];
#pragma unroll
        for (int i = 0; i < BATCH; ++i) {         // 16 independent loads
            int rr = r0 - PAD + half * BATCH + i;
            vv[i] = make_float2(0.f, 0.f);
            if (!EDGE || (rr >= 0 && rr < HH))    // compile-time true interior
                vv[i] = *(const float2*)(ip + (long)rr * WW);
        }
#pragma unroll
        for (int i = 0; i < BATCH; ++i) {
            int r = half * BATCH + i;
#pragma unroll
            for (int j = 0; j < HT; ++j) {
                int t = r - j;                    // compile-time pruned taps
                if (t >= 0 && t < KS) {
                    acc[j].x += vv[i].x * W[t];
                    acc[j].y += vv[i].y * W[t];
                }
            }
        }
    }
#pragma unroll
    for (int j = 0; j < HT; ++j)
        *(float2*)&tile[j * LDSW + PAD + tid * 2] = acc[j];

    __syncthreads();

    // ---- horizontal + clip: thread -> one f4 output per iteration ----
#pragma unroll
    for (int it = 0; it < 4; ++it) {
        int f = it * 256 + tid;                  // f4 index in strip
        int c4 = f & 127;                        // consecutive lanes -> coalesced
        int row = f >> 7;
        const float* lp = &tile[row * LDSW + c4 * 4];  // window start (out col - 12)
        float o0 = 0.f, o1 = 0.f, o2 = 0.f, o3 = 0.f;
#pragma unroll
        for (int q = 0; q < 7; ++q) {            // 7x ds_read_b128
            float4 v = *(const float4*)(lp + 4 * q);
            float vv[4] = {v.x, v.y, v.z, v.w};
#pragma unroll
            for (int e = 0; e < 4; ++e) {
                int wdx = 4 * q + e;             // window index 0..27
                if (wdx - 0 >= 0 && wdx - 0 < KS) o0 += vv[e] * W[wdx];
                if (wdx - 1 >= 0 && wdx - 1 < KS) o1 += vv[e] * W[wdx - 1];
                if (wdx - 2 >= 0 && wdx - 2 < KS) o2 += vv[e] * W[wdx - 2];
                if (wdx - 3 >= 0 && wdx - 3 < KS) o3 += vv[e] * W[wdx - 3];
            }
        }
        float4 ov = make_float4(clamp01(o0), clamp01(o1), clamp01(o2), clamp01(o3));
        *(float4*)(obase + (long)(r0 + row) * WW + c4 * 4) = ov;
    }
}

// (256,8) forced VGPR=32 -> spills (WRITE 98->597MB, 5x slower). Keep (256,4).
__global__ __launch_bounds__(256, 4) void gblur_fused(const float* __restrict__ x,
                                                      float* __restrict__ out) {
    __shared__ float tile[HT * LDSW];            // 17,152 B

    int tid = threadIdx.x;

    // ---- block mapping with bijective XCD swizzle (6144 % 8 == 0) ----
    int b = blockIdx.x;
    const int nwg = NB * CC * (HH / HT);         // 6144
    int per = nwg >> 3;
    int swz = (b & 7) * per + (b >> 3);
    int plane = swz >> 6;                        // 64 strips per plane
    int strip = swz & 63;
    int r0 = strip * HT;

    const float* ibase = x + (long)plane * (HH * WW);
    float*       obase = out + (long)plane * (HH * WW);

    // block-uniform edge test: window [r0-12, r0+19] inside [0,511]?
    if (r0 >= PAD && r0 <= HH - HT - PAD)
        blur_body<false>(ibase, obase, r0, tid, tile);
    else
        blur_body<true>(ibase, obase, r0, tid, tile);
}

extern "C" void kernel_launch(void* const* d_in, const int* in_sizes, int n_in,
                              void* d_out, int out_size, void* d_ws, size_t ws_size,
                              hipStream_t stream) {
    const float* x = (const float*)d_in[0];
    float* out = (float*)d_out;
    const int nwg = NB * CC * (HH / HT);         // 6144 blocks
    gblur_fused<<<nwg, 256, 0, stream>>>(x, out);
}

// Round 9
// 43.570 us; speedup vs baseline: 1.0024x; 1.0024x over previous
//
#include <hip/hip_runtime.h>

#define NB 32
#define CC 3
#define HH 512
#define WW 512
#define KS 25
#define PAD 12
#define HT 8                  // output rows per block (full 512-wide strip)
#define LDSW 536              // 12 halo + 512 + 12 halo floats per LDS row
#define BATCH 16              // vertical rows preloaded per register batch

__device__ __forceinline__ float clamp01(float v) {
    return fminf(fmaxf(v, 0.0f), 1.0f);
}

// EDGE=false: strips 2..61, no bounds checks anywhere (94% of blocks).
template<bool EDGE>
__device__ __forceinline__ void blur_body(const float* __restrict__ ibase,
                                          float* __restrict__ obase,
                                          int r0, int tid, float* tile) {
    constexpr float W[KS] = {
        0.02181520f, 0.02514307f, 0.02862302f, 0.03218484f, 0.03574584f,
        0.03921371f, 0.04249020f, 0.04547544f, 0.04807347f, 0.05019624f,
        0.05176967f, 0.05273727f, 0.05306384f, 0.05273727f, 0.05176967f,
        0.05019624f, 0.04807347f, 0.04547544f, 0.04249020f, 0.03921371f,
        0.03574584f, 0.03218484f, 0.02862302f, 0.02514307f, 0.02181520f};

    // zero left/right halos: 8 rows x 24 floats
    if (tid < HT * 2 * PAD) {
        int r = tid / (2 * PAD);
        int k = tid - r * (2 * PAD);
        tile[r * LDSW + (k < PAD ? k : 512 + k)] = 0.0f;
    }

    // ---- vertical: thread owns float2-column tid for ALL 8 rows ----
    // Round 8's reg-batch was sunk by the scheduler (VGPR stayed 36, ~5 loads
    // in flight). sched_barrier(0) fences the 16-load cluster so all 16
    // global_load_dwordx2 are issued before any FMA consumes them.
    const float* ip = ibase + tid * 2;
    float2 acc[HT];
#pragma unroll
    for (int j = 0; j < HT; ++j) acc[j] = make_float2(0.f, 0.f);

#pragma unroll
    for (int half = 0; half < 2; ++half) {
        float2 vv[BATCH];
#pragma unroll
        for (int i = 0; i < BATCH; ++i) {         // 16 independent loads
            int rr = r0 - PAD + half * BATCH + i;
            vv[i] = make_float2(0.f, 0.f);
            if (!EDGE || (rr >= 0 && rr < HH))    // compile-time true interior
                vv[i] = *(const float2*)(ip + (long)rr * WW);
        }
        __builtin_amdgcn_sched_barrier(0);        // loads stay above this line
#pragma unroll
        for (int i = 0; i < BATCH; ++i) {
            int r = half * BATCH + i;
#pragma unroll
            for (int j = 0; j < HT; ++j) {
                int t = r - j;                    // compile-time pruned taps
                if (t >= 0 && t < KS) {
                    acc[j].x += vv[i].x * W[t];
                    acc[j].y += vv[i].y * W[t];
                }
            }
        }
    }
#pragma unroll
    for (int j = 0; j < HT; ++j)
        *(float2*)&tile[j * LDSW + PAD + tid * 2] = acc[j];

    __syncthreads();

    // ---- horizontal + clip: thread -> one f4 output per iteration ----
#pragma unroll
    for (int it = 0; it < 4; ++it) {
        int f = it * 256 + tid;                  // f4 index in strip
        int c4 = f & 127;                        // consecutive lanes -> coalesced
        int row = f >> 7;
        const float* lp = &tile[row * LDSW + c4 * 4];  // window start (out col - 12)
        float o0 = 0.f, o1 = 0.f, o2 = 0.f, o3 = 0.f;
#pragma unroll
        for (int q = 0; q < 7; ++q) {            // 7x ds_read_b128
            float4 v = *(const float4*)(lp + 4 * q);
            float vv[4] = {v.x, v.y, v.z, v.w};
#pragma unroll
            for (int e = 0; e < 4; ++e) {
                int wdx = 4 * q + e;             // window index 0..27
                if (wdx - 0 >= 0 && wdx - 0 < KS) o0 += vv[e] * W[wdx];
                if (wdx - 1 >= 0 && wdx - 1 < KS) o1 += vv[e] * W[wdx - 1];
                if (wdx - 2 >= 0 && wdx - 2 < KS) o2 += vv[e] * W[wdx - 2];
                if (wdx - 3 >= 0 && wdx - 3 < KS) o3 += vv[e] * W[wdx - 3];
            }
        }
        float4 ov = make_float4(clamp01(o0), clamp01(o1), clamp01(o2), clamp01(o3));
        *(float4*)(obase + (long)(r0 + row) * WW + c4 * 4) = ov;
    }
}

// (256,8) forced VGPR=32 -> spills (WRITE 98->597MB, 5x slower). Keep (256,4).
__global__ __launch_bounds__(256, 4) void gblur_fused(const float* __restrict__ x,
                                                      float* __restrict__ out) {
    __shared__ float tile[HT * LDSW];            // 17,152 B

    int tid = threadIdx.x;

    // ---- block mapping with bijective XCD swizzle (6144 % 8 == 0) ----
    int b = blockIdx.x;
    const int nwg = NB * CC * (HH / HT);         // 6144
    int per = nwg >> 3;
    int swz = (b & 7) * per + (b >> 3);
    int plane = swz >> 6;                        // 64 strips per plane
    int strip = swz & 63;
    int r0 = strip * HT;

    const float* ibase = x + (long)plane * (HH * WW);
    float*       obase = out + (long)plane * (HH * WW);

    // block-uniform edge test: window [r0-12, r0+19] inside [0,511]?
    if (r0 >= PAD && r0 <= HH - HT - PAD)
        blur_body<false>(ibase, obase, r0, tid, tile);
    else
        blur_body<true>(ibase, obase, r0, tid, tile);
}

extern "C" void kernel_launch(void* const* d_in, const int* in_sizes, int n_in,
                              void* d_out, int out_size, void* d_ws, size_t ws_size,
                              hipStream_t stream) {
    const float* x = (const float*)d_in[0];
    float* out = (float*)d_out;
    const int nwg = NB * CC * (HH / HT);         // 6144 blocks
    gblur_fused<<<nwg, 256, 0, stream>>>(x, out);
}

// Round 11
// 41.942 us; speedup vs baseline: 1.0413x; 1.0388x over previous
//
#include <hip/hip_runtime.h>

#define NB 32
#define CC 3
#define HH 512
#define WW 512
#define KS 25
#define PAD 12
#define HT 8                  // output rows per block (full 512-wide strip)
#define LDSW2 268             // words per tile row: 6 halo + 256 + 6 halo (f16 pairs)

typedef __fp16 h2 __attribute__((ext_vector_type(2)));

#if __has_builtin(__builtin_amdgcn_fdot2)
#define FDOT2(a, b, c) __builtin_amdgcn_fdot2((a), (b), (c), false)
#else
#define FDOT2(a, b, c) ((float)(a).x * (float)(b).x + (float)(a).y * (float)(b).y + (c))
#endif

// normalized 1-D gaussian, sigma=9, K=25
__device__ constexpr float Wf[KS] = {
    0.02181520f, 0.02514307f, 0.02862302f, 0.03218484f, 0.03574584f,
    0.03921371f, 0.04249020f, 0.04547544f, 0.04807347f, 0.05019624f,
    0.05176967f, 0.05273727f, 0.05306384f, 0.05273727f, 0.05176967f,
    0.05019624f, 0.04807347f, 0.04547544f, 0.04249020f, 0.03921371f,
    0.03574584f, 0.03218484f, 0.02862302f, 0.02514307f, 0.02181520f};

__device__ constexpr float Wget(int t) {
    return (t >= 0 && t < KS) ? Wf[t] : 0.0f;
}

__device__ __forceinline__ float clamp01(float v) {
    return fminf(fmaxf(v, 0.0f), 1.0f);
}

// EDGE=false: strips 2..61, no bounds checks anywhere (94% of blocks).
template<bool EDGE>
__device__ __forceinline__ void blur_body(const float* __restrict__ ibase,
                                          float* __restrict__ obase,
                                          int r0, int tid, unsigned* tile16) {
    // zero halo words: per row, words 0..5 (cols -12..-1) and 262..267 (512..523)
    if (tid < HT * 12) {
        int r = tid / 12;
        int k = tid - r * 12;
        tile16[r * LDSW2 + (k < 6 ? k : 256 + k)] = 0u;
    }

    // ---- vertical: thread owns f32 cols (2tid, 2tid+1), all 8 rows ----
    // Row pairs packed to f16 along the row axis; 13 dot2/output (vs 25 FMA).
    const float* ip = ibase + tid * 2;
    float accx[HT], accy[HT];
#pragma unroll
    for (int j = 0; j < HT; ++j) { accx[j] = 0.f; accy[j] = 0.f; }

#pragma unroll
    for (int k = 0; k < 16; ++k) {               // 16 row pairs = 32 rows
        int rr0 = r0 - PAD + 2 * k;
        int rr1 = rr0 + 1;
        float2 va = make_float2(0.f, 0.f), vb = make_float2(0.f, 0.f);
        if (!EDGE || (rr0 >= 0 && rr0 < HH)) va = *(const float2*)(ip + (long)rr0 * WW);
        if (!EDGE || (rr1 >= 0 && rr1 < HH)) vb = *(const float2*)(ip + (long)rr1 * WW);
        h2 px = __builtin_amdgcn_cvt_pkrtz(va.x, vb.x);
        h2 py = __builtin_amdgcn_cvt_pkrtz(va.y, vb.y);
#pragma unroll
        for (int j = 0; j < HT; ++j) {
            const int t0 = 2 * k - j;            // tap of pair-lo (compile-time)
            if (t0 >= -1 && t0 <= 24) {
                const h2 wp = {(__fp16)Wget(t0), (__fp16)Wget(t0 + 1)};
                accx[j] = FDOT2(px, wp, accx[j]);
                accy[j] = FDOT2(py, wp, accy[j]);
            }
        }
    }
    // pack adjacent columns into one u32 word per row: word index tid+6
#pragma unroll
    for (int j = 0; j < HT; ++j) {
        h2 w = __builtin_amdgcn_cvt_pkrtz(accx[j], accy[j]);
        tile16[j * LDSW2 + 6 + tid] = __builtin_bit_cast(unsigned, w);
    }

    __syncthreads();

    // ---- horizontal + clip: thread -> 8 consecutive outputs per iteration ----
    // Window = padded f16 [8g, 8g+31] = words [4g, 4g+15] = 4x ds_read_b128,
    // 16B lane stride (conflict-free).
#pragma unroll
    for (int it = 0; it < 2; ++it) {
        int f = it * 256 + tid;
        int g = f & 63;                          // lanes -> adjacent col groups
        int row = f >> 6;                        // wave-uniform
        const unsigned* lp = &tile16[row * LDSW2 + 4 * g];
        h2 pa[16];
#pragma unroll
        for (int q = 0; q < 4; ++q) {
            uint4 c = *(const uint4*)(lp + 4 * q);
            pa[4 * q + 0] = __builtin_bit_cast(h2, c.x);
            pa[4 * q + 1] = __builtin_bit_cast(h2, c.y);
            pa[4 * q + 2] = __builtin_bit_cast(h2, c.z);
            pa[4 * q + 3] = __builtin_bit_cast(h2, c.w);
        }
        float res[8];
#pragma unroll
        for (int j = 0; j < 8; ++j) {
            float o = 0.f;
#pragma unroll
            for (int m = 0; m < 16; ++m) {
                const int t0 = 2 * m - j;        // compile-time
                if (t0 >= -1 && t0 <= 24) {
                    const h2 wp = {(__fp16)Wget(t0), (__fp16)Wget(t0 + 1)};
                    o = FDOT2(pa[m], wp, o);
                }
            }
            res[j] = clamp01(o);
        }
        float* op = obase + (long)(r0 + row) * WW + 8 * g;
        *(float4*)(op + 0) = make_float4(res[0], res[1], res[2], res[3]);
        *(float4*)(op + 4) = make_float4(res[4], res[5], res[6], res[7]);
    }
}

// (256,8) forced VGPR=32 -> spills (WRITE 98->597MB, 5x slower). Keep (256,4).
__global__ __launch_bounds__(256, 4) void gblur_fused(const float* __restrict__ x,
                                                      float* __restrict__ out) {
    __shared__ unsigned tile16[HT * LDSW2];      // 8,576 B

    int tid = threadIdx.x;

    // ---- block mapping with bijective XCD swizzle (6144 % 8 == 0) ----
    int b = blockIdx.x;
    const int nwg = NB * CC * (HH / HT);         // 6144
    int per = nwg >> 3;
    int swz = (b & 7) * per + (b >> 3);
    int plane = swz >> 6;                        // 64 strips per plane
    int strip = swz & 63;
    int r0 = strip * HT;

    const float* ibase = x + (long)plane * (HH * WW);
    float*       obase = out + (long)plane * (HH * WW);

    // block-uniform edge test: window [r0-12, r0+19] inside [0,511]?
    if (r0 >= PAD && r0 <= HH - HT - PAD)
        blur_body<false>(ibase, obase, r0, tid, tile16);
    else
        blur_body<true>(ibase, obase, r0, tid, tile16);
}

extern "C" void kernel_launch(void* const* d_in, const int* in_sizes, int n_in,
                              void* d_out, int out_size, void* d_ws, size_t ws_size,
                              hipStream_t stream) {
    const float* x = (const float*)d_in[0];
    float* out = (float*)d_out;
    const int nwg = NB * CC * (HH / HT);         // 6144 blocks
    gblur_fused<<<nwg, 256, 0, stream>>>(x, out);
}